// Round 8
// baseline (28.162 us; speedup 1.0000x reference)
//
#include <hip/hip_runtime.h>
#include <hip/hip_bf16.h>

#define NB 32        // batch (docs)
#define NT 4096      // tokens per doc
#define NH 256       // hidden
#define NS 256       // MAX_SENTS
#define GY 16        // blocks per doc (grid.y) -> 512 blocks total, 2/CU

// ---------------------------------------------------------------------------
// Fused kernel, amortized: grid (x=NB docs, y=GY), 256 threads (4 waves).
// Each block scans its doc once (int4 + shfl_up + 2-barrier fixup -> LDS),
// then each wave pools 4 sentences: s = (4h+w) + 64m, m=0..3. 16 blocks/doc
// x 16 sentences = 256 slots. Per CU: 2 blocks = ~512 KiB regardless of doc.
// vs R7: scans/doc 64->16, per-wave work averages 4 sentences (tighter retire
// curve), 8 waves/CU with 32 KiB in flight (~3x latency*BW product).
// Invalid sentence slots zero-fill (poisoned d_out fully rewritten).
// ---------------------------------------------------------------------------
__global__ void hie_fused_kernel(const float* __restrict__ x,
                                 const int* __restrict__ batch_x,
                                 float* __restrict__ out) {
    const int b    = blockIdx.x;               // doc
    const int h    = blockIdx.y;               // block-in-doc 0..15
    const int tid  = threadIdx.x;
    const int wid  = tid >> 6;
    const int lane = tid & 63;

    __shared__ int sm_w[5];
    __shared__ int sm_bpos[NS + 1];
    __shared__ int sm_len;

    // ---- phase 1: boundary scan (once per block) ----
    const int  base = tid * 16;
    const int4* rp  = reinterpret_cast<const int4*>(batch_x + (size_t)b * NT + base);
    int flags = 0, cnt = 0;
#pragma unroll
    for (int i = 0; i < 4; ++i) {
        int4 v = rp[i];
        int f0 = (v.x == 1), f1 = (v.y == 1), f2 = (v.z == 1), f3 = (v.w == 1);
        flags |= (f0 << (4 * i)) | (f1 << (4 * i + 1)) | (f2 << (4 * i + 2)) | (f3 << (4 * i + 3));
        cnt   += f0 + f1 + f2 + f3;
    }

    int inc = cnt;
#pragma unroll
    for (int off = 1; off < 64; off <<= 1) {
        int u = __shfl_up(inc, off, 64);
        if (lane >= off) inc += u;
    }
    if (lane == 63) sm_w[wid] = inc;
    __syncthreads();
    if (tid == 0) {
        int run = 0;
#pragma unroll
        for (int w = 0; w < 4; ++w) { int t = sm_w[w]; sm_w[w] = run; run += t; }
        sm_w[4]    = run;
        sm_len     = run > NS ? NS : run;
        sm_bpos[0] = -1;
    }
    __syncthreads();

    int idx = (inc - cnt) + sm_w[wid];
#pragma unroll
    for (int i = 0; i < 16; ++i) {
        if ((flags >> i) & 1) {
            if (idx < NS) sm_bpos[idx + 1] = base + i;
            ++idx;
        }
    }
    __syncthreads();

    if (h == 0 && tid == 0)
        out[(size_t)NB * NS * NH + b] = (float)sm_w[4];   // doc_lens tail

    // ---- phase 2: 4 sentences per wave ----
    const int slot = h * 4 + wid;                          // 0..63
    const int len  = sm_len;

#pragma unroll
    for (int m = 0; m < 4; ++m) {
        const int s = slot + 64 * m;
        float* o = out + ((size_t)b * NS + s) * NH + lane * 4;

        if (s >= len) {
            *reinterpret_cast<float4*>(o) = make_float4(0.f, 0.f, 0.f, 0.f);
            continue;
        }

        const int end   = sm_bpos[s + 1];
        const int start = sm_bpos[s] + 1;
        const int n     = end - start + 1;

        const float4* p = reinterpret_cast<const float4*>(
                              x + ((size_t)b * NT + start) * NH) + lane;
        float4 a0 = make_float4(0.f, 0.f, 0.f, 0.f);
        float4 a1 = make_float4(0.f, 0.f, 0.f, 0.f);
        float4 a2 = make_float4(0.f, 0.f, 0.f, 0.f);
        float4 a3 = make_float4(0.f, 0.f, 0.f, 0.f);

        int k = 0;
        for (; k + 4 <= n; k += 4) {
            float4 v0 = p[0 * (NH / 4)];
            float4 v1 = p[1 * (NH / 4)];
            float4 v2 = p[2 * (NH / 4)];
            float4 v3 = p[3 * (NH / 4)];
            a0.x += v0.x; a0.y += v0.y; a0.z += v0.z; a0.w += v0.w;
            a1.x += v1.x; a1.y += v1.y; a1.z += v1.z; a1.w += v1.w;
            a2.x += v2.x; a2.y += v2.y; a2.z += v2.z; a2.w += v2.w;
            a3.x += v3.x; a3.y += v3.y; a3.z += v3.z; a3.w += v3.w;
            p += 4 * (NH / 4);
        }
        for (; k < n; ++k) {
            float4 v0 = p[0];
            a0.x += v0.x; a0.y += v0.y; a0.z += v0.z; a0.w += v0.w;
            p += NH / 4;
        }

        const float inv = 1.0f / (float)n;
        *reinterpret_cast<float4*>(o) =
            make_float4((a0.x + a1.x + a2.x + a3.x) * inv,
                        (a0.y + a1.y + a2.y + a3.y) * inv,
                        (a0.z + a1.z + a2.z + a3.z) * inv,
                        (a0.w + a1.w + a2.w + a3.w) * inv);
    }
}

extern "C" void kernel_launch(void* const* d_in, const int* in_sizes, int n_in,
                              void* d_out, int out_size, void* d_ws, size_t ws_size,
                              hipStream_t stream) {
    const float* hie_ins = (const float*)d_in[0];
    const int*   batch_x = (const int*)d_in[1];
    float*       out     = (float*)d_out;

    hie_fused_kernel<<<dim3(NB, GY), dim3(256), 0, stream>>>(hie_ins, batch_x, out);
}

// Round 9
// 27.703 us; speedup vs baseline: 1.0166x; 1.0166x over previous
//
#include <hip/hip_runtime.h>
#include <hip/hip_bf16.h>

#define NB 32        // batch (docs)
#define NT 4096      // tokens per doc
#define NH 256       // hidden
#define NS 256       // MAX_SENTS

// ---------------------------------------------------------------------------
// Fused kernel (R7 structure — best measured). Grid (x=NB docs, y=NS/4),
// 256 threads (4 waves), 2048 blocks = 8/CU, all resident.
// Phase 1: block-redundant boundary scan: 4x int4 flag loads, shfl_up wave
//   scan, 2-barrier cross-wave fixup, ctz-based boundary walk (avg ~1.2
//   set bits per thread instead of a 16-iter branchy loop).
// Phase 2: one sentence per wave (s = wid*64 + g), float4 lane loads,
//   unroll-4, float4 store of the mean. Invalid sentences zero-fill.
// Per CU: one doc x 32 equal-length sentences -> byte-uniform waves.
// ---------------------------------------------------------------------------
__global__ void __launch_bounds__(256, 8)
hie_fused_kernel(const float* __restrict__ x,
                 const int* __restrict__ batch_x,
                 float* __restrict__ out) {
    const int b    = blockIdx.x;               // doc
    const int g    = blockIdx.y;               // stripe index 0..63
    const int tid  = threadIdx.x;
    const int wid  = tid >> 6;
    const int lane = tid & 63;

    __shared__ int sm_w[5];
    __shared__ int sm_bpos[NS + 1];
    __shared__ int sm_len;

    // ---- phase 1: boundary scan ----
    const int  base = tid * 16;
    const int4* rp  = reinterpret_cast<const int4*>(batch_x + (size_t)b * NT + base);
    unsigned int flags = 0;
#pragma unroll
    for (int i = 0; i < 4; ++i) {
        int4 v = rp[i];
        flags |= ((unsigned)(v.x == 1) << (4 * i))
               | ((unsigned)(v.y == 1) << (4 * i + 1))
               | ((unsigned)(v.z == 1) << (4 * i + 2))
               | ((unsigned)(v.w == 1) << (4 * i + 3));
    }
    const int cnt = __popc(flags);

    int inc = cnt;
#pragma unroll
    for (int off = 1; off < 64; off <<= 1) {
        int u = __shfl_up(inc, off, 64);
        if (lane >= off) inc += u;
    }
    if (lane == 63) sm_w[wid] = inc;
    __syncthreads();
    if (tid == 0) {
        int run = 0;
#pragma unroll
        for (int w = 0; w < 4; ++w) { int t = sm_w[w]; sm_w[w] = run; run += t; }
        sm_w[4]    = run;
        sm_len     = run > NS ? NS : run;
        sm_bpos[0] = -1;
    }
    __syncthreads();

    int idx = (inc - cnt) + sm_w[wid];
    unsigned int f = flags;
    while (f) {
        int i = __builtin_ctz(f);
        f &= f - 1;
        if (idx < NS) sm_bpos[idx + 1] = base + i;
        ++idx;
    }
    __syncthreads();

    if (g == 0 && tid == 0)
        out[(size_t)NB * NS * NH + b] = (float)sm_w[4];   // doc_lens tail

    // ---- phase 2: one sentence per wave (striped: s = wid*64 + g) ----
    const int s = wid * 64 + g;
    float* o = out + ((size_t)b * NS + s) * NH + lane * 4;

    if (s >= sm_len) {
        *reinterpret_cast<float4*>(o) = make_float4(0.f, 0.f, 0.f, 0.f);
        return;
    }

    const int end   = sm_bpos[s + 1];
    const int start = sm_bpos[s] + 1;
    const int n     = end - start + 1;

    const float4* p = reinterpret_cast<const float4*>(
                          x + ((size_t)b * NT + start) * NH) + lane;
    float4 a0 = make_float4(0.f, 0.f, 0.f, 0.f);
    float4 a1 = make_float4(0.f, 0.f, 0.f, 0.f);
    float4 a2 = make_float4(0.f, 0.f, 0.f, 0.f);
    float4 a3 = make_float4(0.f, 0.f, 0.f, 0.f);

    int k = 0;
    for (; k + 4 <= n; k += 4) {
        float4 v0 = p[0 * (NH / 4)];
        float4 v1 = p[1 * (NH / 4)];
        float4 v2 = p[2 * (NH / 4)];
        float4 v3 = p[3 * (NH / 4)];
        a0.x += v0.x; a0.y += v0.y; a0.z += v0.z; a0.w += v0.w;
        a1.x += v1.x; a1.y += v1.y; a1.z += v1.z; a1.w += v1.w;
        a2.x += v2.x; a2.y += v2.y; a2.z += v2.z; a2.w += v2.w;
        a3.x += v3.x; a3.y += v3.y; a3.z += v3.z; a3.w += v3.w;
        p += 4 * (NH / 4);
    }
    for (; k < n; ++k) {
        float4 v0 = p[0];
        a0.x += v0.x; a0.y += v0.y; a0.z += v0.z; a0.w += v0.w;
        p += NH / 4;
    }

    const float inv = 1.0f / (float)n;
    *reinterpret_cast<float4*>(o) =
        make_float4((a0.x + a1.x + a2.x + a3.x) * inv,
                    (a0.y + a1.y + a2.y + a3.y) * inv,
                    (a0.z + a1.z + a2.z + a3.z) * inv,
                    (a0.w + a1.w + a2.w + a3.w) * inv);
}

extern "C" void kernel_launch(void* const* d_in, const int* in_sizes, int n_in,
                              void* d_out, int out_size, void* d_ws, size_t ws_size,
                              hipStream_t stream) {
    const float* hie_ins = (const float*)d_in[0];
    const int*   batch_x = (const int*)d_in[1];
    float*       out     = (float*)d_out;

    hie_fused_kernel<<<dim3(NB, NS / 4), dim3(256), 0, stream>>>(hie_ins, batch_x, out);
}